// Round 9
// baseline (2795.410 us; speedup 1.0000x reference)
//
#include <hip/hip_runtime.h>
#include <math.h>

// One persistent kernel, 512 blocks x 256 thr (2 blocks/CU guaranteed by
// __launch_bounds__(256,2), ~zero LDS). Hand-rolled device-scope grid
// barrier (cnt+gen in ws, zeroed by hipMemsetAsync each call).
// GEMM stages: out[i,l] = sum_m act[i,m]*W[l,m]; per unit a wave owns 4
// consecutive W rows streamed sequentially (float4, next-chunk prefetch),
// acts read from L2, in-wave butterfly k-reduce, k-split planes P[s][i][l].
// Small phases (init/attn/redln/gelu) are inline grid-stride phases.

#define AGENT __HIP_MEMORY_SCOPE_AGENT

__device__ __forceinline__ unsigned aload(unsigned* p) {
    return __hip_atomic_load(p, __ATOMIC_RELAXED, AGENT);
}

__device__ __forceinline__ void gbar(unsigned* cnt, unsigned* gen) {
    __syncthreads();
    if (threadIdx.x == 0) {
        __threadfence();
        unsigned g = aload(gen);
        unsigned arrived =
            __hip_atomic_fetch_add(cnt, 1u, __ATOMIC_ACQ_REL, AGENT) + 1;
        if (arrived == gridDim.x) {
            __hip_atomic_store(cnt, 0u, __ATOMIC_RELAXED, AGENT);
            __hip_atomic_fetch_add(gen, 1u, __ATOMIC_ACQ_REL, AGENT);
        } else {
            while (aload(gen) == g) __builtin_amdgcn_s_sleep(2);
        }
        __threadfence();
    }
    __syncthreads();
}

template <int NR>
__device__ __forceinline__ void gemv(const float* __restrict__ W,
                                     const float* __restrict__ act,
                                     float* __restrict__ P,
                                     int L, int K, int SLAB) {
    const int lane = threadIdx.x & 63, wv = threadIdx.x >> 6;
    const int LT = L >> 4, NS = K / SLAB, total = LT * NS;
    for (int u = blockIdx.x; u < total; u += gridDim.x) {
        const int lt = u % LT, sx = u / LT;
        const int l0 = lt * 16 + wv * 4;
        const int k0 = sx * SLAB;
        const float* Wp = W + (size_t)l0 * K + k0;
        const float* Ap = act + k0;
        float acc[NR][4];
#pragma unroll
        for (int i = 0; i < NR; ++i) {
            acc[i][0] = 0.f; acc[i][1] = 0.f; acc[i][2] = 0.f; acc[i][3] = 0.f;
        }
        float4 w4[4], wn[4];
#pragma unroll
        for (int r = 0; r < 4; ++r)
            w4[r] = *reinterpret_cast<const float4*>(Wp + (size_t)r * K + lane * 4);
        const int NC = SLAB >> 8;
        for (int c = 0; c < NC; ++c) {
            if (c + 1 < NC) {
#pragma unroll
                for (int r = 0; r < 4; ++r)
                    wn[r] = *reinterpret_cast<const float4*>(
                        Wp + (size_t)r * K + (c + 1) * 256 + lane * 4);
            }
            const float* ap = Ap + c * 256 + lane * 4;
#pragma unroll
            for (int i = 0; i < NR; ++i) {
                const float4 a4 = *reinterpret_cast<const float4*>(ap + (size_t)i * K);
                acc[i][0] += a4.x * w4[0].x + a4.y * w4[0].y + a4.z * w4[0].z + a4.w * w4[0].w;
                acc[i][1] += a4.x * w4[1].x + a4.y * w4[1].y + a4.z * w4[1].z + a4.w * w4[1].w;
                acc[i][2] += a4.x * w4[2].x + a4.y * w4[2].y + a4.z * w4[2].z + a4.w * w4[2].w;
                acc[i][3] += a4.x * w4[3].x + a4.y * w4[3].y + a4.z * w4[3].z + a4.w * w4[3].w;
            }
#pragma unroll
            for (int r = 0; r < 4; ++r) w4[r] = wn[r];
        }
        float vout = 0.f, vout2 = 0.f;
#pragma unroll
        for (int i = 0; i < NR; ++i)
#pragma unroll
            for (int r = 0; r < 4; ++r) {
                float v = acc[i][r];
#pragma unroll
                for (int off = 32; off; off >>= 1) v += __shfl_xor(v, off);
                if (i < 16) { if (lane == i * 4 + r) vout = v; }
                else        { if (lane == r)         vout2 = v; }
            }
        const size_t pb = (size_t)sx * NR * L + l0;
        P[pb + (size_t)(lane >> 2) * L + (lane & 3)] = vout;
        if (NR > 16 && lane < 4) P[pb + (size_t)16 * L + lane] = vout2;
    }
}

__device__ __forceinline__ void redln_f(const float* __restrict__ P, int S,
                                        int rowoff, int NRL,
                                        const float* __restrict__ fb,
                                        float* __restrict__ ss,
                                        const float* __restrict__ g,
                                        const float* __restrict__ b,
                                        float* __restrict__ lnout,
                                        float* shred) {
    const int row = blockIdx.x;
    if (row >= 17) return;
    const int tid = threadIdx.x;
    const int base = row * 2048;
    float vv[8];
    float s = 0.f, q = 0.f;
#pragma unroll
    for (int c = 0; c < 8; ++c) {
        int col = tid + c * 256;
        float xv = ss[base + col];
        if (row >= rowoff) {
            const float* pp = P + (size_t)(row - rowoff) * 2048 + col;
            for (int y = 0; y < S; ++y) xv += pp[(size_t)y * NRL];
        }
        if (fb != nullptr) xv += fb[col];
        ss[base + col] = xv;
        vv[c] = xv;
        s += xv;
        q += xv * xv;
    }
#pragma unroll
    for (int off = 32; off; off >>= 1) {
        s += __shfl_xor(s, off);
        q += __shfl_xor(q, off);
    }
    int wvi = tid >> 6;
    if ((tid & 63) == 0) { shred[wvi] = s; shred[4 + wvi] = q; }
    __syncthreads();
    s = shred[0] + shred[1] + shred[2] + shred[3];
    q = shred[4] + shred[5] + shred[6] + shred[7];
    float mean = s * (1.f / 2048.f);
    float var = q * (1.f / 2048.f) - mean * mean;
    float rstd = rsqrtf(var + 1e-5f);
#pragma unroll
    for (int c = 0; c < 8; ++c) {
        int col = tid + c * 256;
        lnout[base + col] = (vv[c] - mean) * rstd * g[col] + b[col];
    }
    __syncthreads();
}

__global__ __launch_bounds__(256, 2) void mega(
    const float* __restrict__ x, const float* __restrict__ weight,
    const float* __restrict__ bias, const float* __restrict__ cls,
    const float* __restrict__ Wqkv, const float* __restrict__ Wo,
    const float* __restrict__ ln1_g, const float* __restrict__ ln1_b,
    const float* __restrict__ ln2_g, const float* __restrict__ ln2_b,
    const float* __restrict__ ln3_g, const float* __restrict__ ln3_b,
    const float* __restrict__ fc1_w, const float* __restrict__ fc1_b,
    const float* __restrict__ fc2_w, const float* __restrict__ fc2_b,
    float* __restrict__ out, float* __restrict__ ws, unsigned* __restrict__ bar) {
    __shared__ float shred[8];
    unsigned* cnt = bar;
    unsigned* gen = bar + 1;

    float* ss     = ws;                 // 34816
    float* altx   = ws + 34816;         // 32768
    float* imv    = ws + 67584;         // 34816
    float* tbuf   = ws + 102400;        // 139264
    float* ln1buf = ws + 241664;        // 34816
    float* ln2buf = ws + 276480;        // 34816
    float* Pq     = ws + 311296;        // 417792
    float* Pf     = ws + 729088;        // 278528

    // ---- phase 0: init ss = bias (+cls), altx ----
    for (int idx = blockIdx.x * 256 + threadIdx.x; idx < 17 * 2048;
         idx += gridDim.x * 256) {
        int r = idx >> 11, m = idx & 2047;
        float v = bias[idx];
        if (r == 0) v += cls[m];
        ss[idx] = v;
        if (idx < 16 * 2048) {
            int i = idx >> 11;
            int c1 = m >> 6, c2 = m & 63;
            const float* p = x + (size_t)(c2 * 32 + c1) * 160 + i * 10;
            float s = 0.f;
#pragma unroll
            for (int j = 0; j < 10; ++j) s += p[j];
            altx[idx] = s * 0.1f;
        }
    }
    gbar(cnt, gen);

    // ---- GEMM1: ss[1:17] += altx @ weight.T (4 planes [16][2048]) ----
    gemv<16>(weight, altx, Pq, 2048, 2048, 512);
    gbar(cnt, gen);
    redln_f(Pq, 4, 1, 32768, nullptr, ss, ln1_g, ln1_b, ln1buf, shred);
    gbar(cnt, gen);

    for (int k = 0; k < 4; ++k) {
        // qkv (4 planes [17][6144])
        gemv<17>(Wqkv + (size_t)k * 12582912, ln1buf, Pq, 6144, 2048, 512);
        gbar(cnt, gen);
        // attn: 16 blocks x 64 lanes; sums 4 planes inline
        if (blockIdx.x < 16 && threadIdx.x < 64) {
            const int h = blockIdx.x, lane = threadIdx.x;
            const float scale = 0.08838834764831845f;
            float run0 = 0.f, run1 = 0.f;
            for (int i = 0; i < 17; ++i) {
                const size_t idx = (size_t)i * 6144 + h * 128;
                float q0 = 0.f, q1 = 0.f, k0 = 0.f, k1 = 0.f, v0 = 0.f, v1 = 0.f;
#pragma unroll
                for (int s = 0; s < 4; ++s) {
                    const float* base = Pq + (size_t)s * 104448 + idx;
                    q0 += base[lane];        q1 += base[lane + 64];
                    k0 += base[2048 + lane]; k1 += base[2048 + lane + 64];
                    v0 += base[4096 + lane]; v1 += base[4096 + lane + 64];
                }
                float p = q0 * k0 + q1 * k1;
#pragma unroll
                for (int off = 32; off; off >>= 1) p += __shfl_xor(p, off);
                float rsa = p * scale;
                float iv0 = rsa * v0, iv1 = rsa * v1;
                float o0, o1;
                if (i < 16) { run0 += iv0; run1 += iv1; o0 = run0; o1 = run1; }
                else        { o0 = iv0; o1 = iv1; }
                imv[(size_t)i * 2048 + h * 128 + lane] = o0;
                imv[(size_t)i * 2048 + h * 128 + lane + 64] = o1;
            }
        }
        gbar(cnt, gen);
        // Wo (4 planes [17][2048])
        gemv<17>(Wo + (size_t)k * 4194304, imv, Pq, 2048, 2048, 512);
        gbar(cnt, gen);
        redln_f(Pq, 4, 0, 34816, nullptr, ss, ln2_g, ln2_b, ln2buf, shred);
        gbar(cnt, gen);
        // fc1 (2 planes [17][8192], raw)
        gemv<17>(fc1_w, ln2buf, Pf, 8192, 2048, 1024);
        gbar(cnt, gen);
        // gelu: tbuf = gelu(Pf0+Pf1 + fc1_b)
        for (int idx = blockIdx.x * 256 + threadIdx.x; idx < 139264;
             idx += gridDim.x * 256) {
            float s = fc1_b[idx & 8191] + Pf[idx] + Pf[139264 + idx];
            tbuf[idx] = 0.5f * s * (1.f + erff(s * 0.70710678f));
        }
        gbar(cnt, gen);
        // fc2 (4 planes [17][2048])
        gemv<17>(fc2_w, tbuf, Pq, 2048, 8192, 2048);
        gbar(cnt, gen);
        if (k < 3)
            redln_f(Pq, 4, 0, 34816, fc2_b, ss, ln1_g, ln1_b, ln1buf, shred);
        else
            redln_f(Pq, 4, 0, 34816, fc2_b, ss, ln3_g, ln3_b, out, shred);
        gbar(cnt, gen);
    }
}

extern "C" void kernel_launch(void* const* d_in, const int* in_sizes, int n_in,
                              void* d_out, int out_size, void* d_ws, size_t ws_size,
                              hipStream_t stream) {
    const float* x      = (const float*)d_in[0];
    const float* weight = (const float*)d_in[1];
    const float* bias   = (const float*)d_in[2];
    const float* cls    = (const float*)d_in[3];
    const float* Wqkv   = (const float*)d_in[4];
    const float* Wo     = (const float*)d_in[5];
    const float* ln1_g  = (const float*)d_in[6];
    const float* ln1_b  = (const float*)d_in[7];
    const float* ln2_g  = (const float*)d_in[8];
    const float* ln2_b  = (const float*)d_in[9];
    const float* ln3_g  = (const float*)d_in[10];
    const float* ln3_b  = (const float*)d_in[11];
    const float* fc1_w  = (const float*)d_in[12];
    const float* fc1_b  = (const float*)d_in[13];
    const float* fc2_w  = (const float*)d_in[14];
    const float* fc2_b  = (const float*)d_in[15];
    float* out = (float*)d_out;
    float* ws  = (float*)d_ws;
    unsigned* bar = (unsigned*)(ws + 1007616);

    hipMemsetAsync(bar, 0, 8, stream);
    mega<<<512, 256, 0, stream>>>(x, weight, bias, cls, Wqkv, Wo,
                                  ln1_g, ln1_b, ln2_g, ln2_b, ln3_g, ln3_b,
                                  fc1_w, fc1_b, fc2_w, fc2_b, out, ws, bar);
}

// Round 11
// 1402.797 us; speedup vs baseline: 1.9927x; 1.9927x over previous
//
#include <hip/hip_runtime.h>
#include <math.h>

// One persistent kernel, 256 blocks x 512 thr (8 waves). __launch_bounds__(512)
// forces VGPR <= 256 (8-wave block needs 2 waves/SIMD) -> no spill (body needs
// ~170) and 256 blocks <= 256 CUs -> all resident -> grid barrier safe.
// R10 deadlocked: uncapped VGPR >256 -> 1 block/CU -> 512-block grid never
// co-resident. R9 spilled: (256,2) capped VGPR=128 (WRITE_SIZE 147MB scratch).
// gemv: wave owns 4 consecutive W rows streamed sequentially (float4),
// acts from L2, in-wave butterfly k-reduce, k-split planes P[s][i][l].
// Small phases (init/attn/redln/gelu) inline between grid barriers.

#define AGENT __HIP_MEMORY_SCOPE_AGENT

__device__ __forceinline__ unsigned aload(unsigned* p) {
    return __hip_atomic_load(p, __ATOMIC_RELAXED, AGENT);
}

__device__ __forceinline__ void gbar(unsigned* cnt, unsigned* gen) {
    __syncthreads();
    if (threadIdx.x == 0) {
        __threadfence();
        unsigned g = aload(gen);
        unsigned arrived =
            __hip_atomic_fetch_add(cnt, 1u, __ATOMIC_ACQ_REL, AGENT) + 1;
        if (arrived == gridDim.x) {
            __hip_atomic_store(cnt, 0u, __ATOMIC_RELAXED, AGENT);
            __hip_atomic_fetch_add(gen, 1u, __ATOMIC_ACQ_REL, AGENT);
        } else {
            while (aload(gen) == g) __builtin_amdgcn_s_sleep(2);
        }
        __threadfence();
    }
    __syncthreads();
}

// block = 8 waves; wave wv owns rows lt*32 + wv*4 .. +3; unit = (l-tile, k-slab)
template <int NR>
__device__ __forceinline__ void gemv(const float* __restrict__ W,
                                     const float* __restrict__ act,
                                     float* __restrict__ P,
                                     int L, int K, int SLAB) {
    const int lane = threadIdx.x & 63, wv = threadIdx.x >> 6;
    const int LT = L >> 5, NS = K / SLAB, total = LT * NS;
    for (int u = blockIdx.x; u < total; u += gridDim.x) {
        const int lt = u % LT, sx = u / LT;
        const int l0 = lt * 32 + wv * 4;
        const int k0 = sx * SLAB;
        const float* Wp = W + (size_t)l0 * K + k0;
        const float* Ap = act + k0;
        float acc[NR][4];
#pragma unroll
        for (int i = 0; i < NR; ++i) {
            acc[i][0] = 0.f; acc[i][1] = 0.f; acc[i][2] = 0.f; acc[i][3] = 0.f;
        }
        for (int kk = 0; kk < SLAB; kk += 256) {
            const int idx = kk + lane * 4;
            const float4 w40 = *reinterpret_cast<const float4*>(Wp + idx);
            const float4 w41 = *reinterpret_cast<const float4*>(Wp + (size_t)K + idx);
            const float4 w42 = *reinterpret_cast<const float4*>(Wp + (size_t)2 * K + idx);
            const float4 w43 = *reinterpret_cast<const float4*>(Wp + (size_t)3 * K + idx);
#pragma unroll
            for (int i = 0; i < NR; ++i) {
                const float4 a4 =
                    *reinterpret_cast<const float4*>(Ap + (size_t)i * K + idx);
                acc[i][0] += a4.x * w40.x + a4.y * w40.y + a4.z * w40.z + a4.w * w40.w;
                acc[i][1] += a4.x * w41.x + a4.y * w41.y + a4.z * w41.z + a4.w * w41.w;
                acc[i][2] += a4.x * w42.x + a4.y * w42.y + a4.z * w42.z + a4.w * w42.w;
                acc[i][3] += a4.x * w43.x + a4.y * w43.y + a4.z * w43.z + a4.w * w43.w;
            }
        }
        float vout = 0.f, vout2 = 0.f;
#pragma unroll
        for (int i = 0; i < NR; ++i)
#pragma unroll
            for (int r = 0; r < 4; ++r) {
                float v = acc[i][r];
#pragma unroll
                for (int off = 32; off; off >>= 1) v += __shfl_xor(v, off);
                if (i < 16) { if (lane == i * 4 + r) vout = v; }
                else        { if (lane == r)         vout2 = v; }
            }
        const size_t pb = (size_t)sx * NR * L + l0;
        P[pb + (size_t)(lane >> 2) * L + (lane & 3)] = vout;
        if (NR > 16 && lane < 4) P[pb + (size_t)16 * L + lane] = vout2;
    }
}

// 512 threads: each owns 4 cols of the 2048-wide row
__device__ __forceinline__ void redln_f(const float* __restrict__ P, int S,
                                        int rowoff, int NRL,
                                        const float* __restrict__ fb,
                                        float* __restrict__ ss,
                                        const float* __restrict__ g,
                                        const float* __restrict__ b,
                                        float* __restrict__ lnout,
                                        float* shred) {
    const int row = blockIdx.x;
    if (row >= 17) return;
    const int tid = threadIdx.x;
    const int base = row * 2048;
    float vv[4];
    float s = 0.f, q = 0.f;
#pragma unroll
    for (int c = 0; c < 4; ++c) {
        int col = tid + c * 512;
        float xv = ss[base + col];
        if (row >= rowoff) {
            const float* pp = P + (size_t)(row - rowoff) * 2048 + col;
            for (int y = 0; y < S; ++y) xv += pp[(size_t)y * NRL];
        }
        if (fb != nullptr) xv += fb[col];
        ss[base + col] = xv;
        vv[c] = xv;
        s += xv;
        q += xv * xv;
    }
#pragma unroll
    for (int off = 32; off; off >>= 1) {
        s += __shfl_xor(s, off);
        q += __shfl_xor(q, off);
    }
    int wvi = tid >> 6;
    if ((tid & 63) == 0) { shred[wvi] = s; shred[8 + wvi] = q; }
    __syncthreads();
    s = 0.f; q = 0.f;
#pragma unroll
    for (int w = 0; w < 8; ++w) { s += shred[w]; q += shred[8 + w]; }
    float mean = s * (1.f / 2048.f);
    float var = q * (1.f / 2048.f) - mean * mean;
    float rstd = rsqrtf(var + 1e-5f);
#pragma unroll
    for (int c = 0; c < 4; ++c) {
        int col = tid + c * 512;
        lnout[base + col] = (vv[c] - mean) * rstd * g[col] + b[col];
    }
    __syncthreads();
}

__global__ __launch_bounds__(512) void mega(
    const float* __restrict__ x, const float* __restrict__ weight,
    const float* __restrict__ bias, const float* __restrict__ cls,
    const float* __restrict__ Wqkv, const float* __restrict__ Wo,
    const float* __restrict__ ln1_g, const float* __restrict__ ln1_b,
    const float* __restrict__ ln2_g, const float* __restrict__ ln2_b,
    const float* __restrict__ ln3_g, const float* __restrict__ ln3_b,
    const float* __restrict__ fc1_w, const float* __restrict__ fc1_b,
    const float* __restrict__ fc2_w, const float* __restrict__ fc2_b,
    float* __restrict__ out, float* __restrict__ ws, unsigned* __restrict__ bar) {
    __shared__ float shred[16];
    unsigned* cnt = bar;
    unsigned* gen = bar + 1;

    float* ss     = ws;                 // 34816
    float* altx   = ws + 34816;         // 32768
    float* imv    = ws + 67584;         // 34816
    float* tbuf   = ws + 102400;        // 139264
    float* ln1buf = ws + 241664;        // 34816
    float* ln2buf = ws + 276480;        // 34816
    float* Pq     = ws + 311296;        // 417792
    float* Pf     = ws + 729088;        // 278528

    // ---- phase 0: init ss = bias (+cls), altx ----
    for (int idx = blockIdx.x * 512 + threadIdx.x; idx < 17 * 2048;
         idx += gridDim.x * 512) {
        int r = idx >> 11, m = idx & 2047;
        float v = bias[idx];
        if (r == 0) v += cls[m];
        ss[idx] = v;
        if (idx < 16 * 2048) {
            int i = idx >> 11;
            int c1 = m >> 6, c2 = m & 63;
            const float* p = x + (size_t)(c2 * 32 + c1) * 160 + i * 10;
            float s = 0.f;
#pragma unroll
            for (int j = 0; j < 10; ++j) s += p[j];
            altx[idx] = s * 0.1f;
        }
    }
    gbar(cnt, gen);

    // ---- GEMM1: ss[1:17] += altx @ weight.T (4 planes [16][2048]) ----
    gemv<16>(weight, altx, Pq, 2048, 2048, 512);
    gbar(cnt, gen);
    redln_f(Pq, 4, 1, 32768, nullptr, ss, ln1_g, ln1_b, ln1buf, shred);
    gbar(cnt, gen);

    for (int k = 0; k < 4; ++k) {
        // qkv (4 planes [17][6144])
        gemv<17>(Wqkv + (size_t)k * 12582912, ln1buf, Pq, 6144, 2048, 512);
        gbar(cnt, gen);
        // attn: blocks 0..15, first wave only; sums 4 planes inline
        if (blockIdx.x < 16 && threadIdx.x < 64) {
            const int h = blockIdx.x, lane = threadIdx.x;
            const float scale = 0.08838834764831845f;
            float run0 = 0.f, run1 = 0.f;
            for (int i = 0; i < 17; ++i) {
                const size_t idx = (size_t)i * 6144 + h * 128;
                float q0 = 0.f, q1 = 0.f, k0 = 0.f, k1 = 0.f, v0 = 0.f, v1 = 0.f;
#pragma unroll
                for (int s = 0; s < 4; ++s) {
                    const float* base = Pq + (size_t)s * 104448 + idx;
                    q0 += base[lane];        q1 += base[lane + 64];
                    k0 += base[2048 + lane]; k1 += base[2048 + lane + 64];
                    v0 += base[4096 + lane]; v1 += base[4096 + lane + 64];
                }
                float p = q0 * k0 + q1 * k1;
#pragma unroll
                for (int off = 32; off; off >>= 1) p += __shfl_xor(p, off);
                float rsa = p * scale;
                float iv0 = rsa * v0, iv1 = rsa * v1;
                float o0, o1;
                if (i < 16) { run0 += iv0; run1 += iv1; o0 = run0; o1 = run1; }
                else        { o0 = iv0; o1 = iv1; }
                imv[(size_t)i * 2048 + h * 128 + lane] = o0;
                imv[(size_t)i * 2048 + h * 128 + lane + 64] = o1;
            }
        }
        gbar(cnt, gen);
        // Wo (4 planes [17][2048])
        gemv<17>(Wo + (size_t)k * 4194304, imv, Pq, 2048, 2048, 512);
        gbar(cnt, gen);
        redln_f(Pq, 4, 0, 34816, nullptr, ss, ln2_g, ln2_b, ln2buf, shred);
        gbar(cnt, gen);
        // fc1 (2 planes [17][8192], raw)
        gemv<17>(fc1_w, ln2buf, Pf, 8192, 2048, 1024);
        gbar(cnt, gen);
        // gelu: tbuf = gelu(Pf0+Pf1 + fc1_b)
        for (int idx = blockIdx.x * 512 + threadIdx.x; idx < 139264;
             idx += gridDim.x * 512) {
            float s = fc1_b[idx & 8191] + Pf[idx] + Pf[139264 + idx];
            tbuf[idx] = 0.5f * s * (1.f + erff(s * 0.70710678f));
        }
        gbar(cnt, gen);
        // fc2 (4 planes [17][2048])
        gemv<17>(fc2_w, tbuf, Pq, 2048, 8192, 2048);
        gbar(cnt, gen);
        if (k < 3)
            redln_f(Pq, 4, 0, 34816, fc2_b, ss, ln1_g, ln1_b, ln1buf, shred);
        else
            redln_f(Pq, 4, 0, 34816, fc2_b, ss, ln3_g, ln3_b, out, shred);
        gbar(cnt, gen);
    }
}

extern "C" void kernel_launch(void* const* d_in, const int* in_sizes, int n_in,
                              void* d_out, int out_size, void* d_ws, size_t ws_size,
                              hipStream_t stream) {
    const float* x      = (const float*)d_in[0];
    const float* weight = (const float*)d_in[1];
    const float* bias   = (const float*)d_in[2];
    const float* cls    = (const float*)d_in[3];
    const float* Wqkv   = (const float*)d_in[4];
    const float* Wo     = (const float*)d_in[5];
    const float* ln1_g  = (const float*)d_in[6];
    const float* ln1_b  = (const float*)d_in[7];
    const float* ln2_g  = (const float*)d_in[8];
    const float* ln2_b  = (const float*)d_in[9];
    const float* ln3_g  = (const float*)d_in[10];
    const float* ln3_b  = (const float*)d_in[11];
    const float* fc1_w  = (const float*)d_in[12];
    const float* fc1_b  = (const float*)d_in[13];
    const float* fc2_w  = (const float*)d_in[14];
    const float* fc2_b  = (const float*)d_in[15];
    float* out = (float*)d_out;
    float* ws  = (float*)d_ws;
    unsigned* bar = (unsigned*)(ws + 1007616);

    hipMemsetAsync(bar, 0, 8, stream);
    mega<<<256, 512, 0, stream>>>(x, weight, bias, cls, Wqkv, Wo,
                                  ln1_g, ln1_b, ln2_g, ln2_b, ln3_g, ln3_b,
                                  fc1_w, fc1_b, fc2_w, fc2_b, out, ws, bar);
}

// Round 12
// 1394.173 us; speedup vs baseline: 2.0051x; 1.0062x over previous
//
#include <hip/hip_runtime.h>
#include <math.h>

// One persistent kernel, 256 blocks x 1024 thr (16 waves).
// __launch_bounds__(1024) HW-forces VGPR<=128 (16-wave block needs 4
// waves/SIMD); gemv restructured so the body needs only ~85 VGPR -> no spill
// (R9/R11 spilled: compiler picks 128 and acc[17][4]+loads needs ~170).
// Wave = (rowgroup rg -> 4 W rows) x (quarter qt -> 5 act rows, boundary rows
// overlap; duplicates are bitwise-identical double-writes). Block = 16 W rows.
// Per chunk: 9 float4 loads issued together, then 80 FMA. k-split planes
// P[s][i][l]; small phases (init/attn/redln/gelu) inline between grid barriers.

#define AGENT __HIP_MEMORY_SCOPE_AGENT

__device__ __forceinline__ unsigned aload(unsigned* p) {
    return __hip_atomic_load(p, __ATOMIC_RELAXED, AGENT);
}

__device__ __forceinline__ void gbar(unsigned* cnt, unsigned* gen) {
    __syncthreads();
    if (threadIdx.x == 0) {
        __threadfence();
        unsigned g = aload(gen);
        unsigned arrived =
            __hip_atomic_fetch_add(cnt, 1u, __ATOMIC_ACQ_REL, AGENT) + 1;
        if (arrived == gridDim.x) {
            __hip_atomic_store(cnt, 0u, __ATOMIC_RELAXED, AGENT);
            __hip_atomic_fetch_add(gen, 1u, __ATOMIC_ACQ_REL, AGENT);
        } else {
            while (aload(gen) == g) __builtin_amdgcn_s_sleep(2);
        }
        __threadfence();
    }
    __syncthreads();
}

// block: 16 waves; wave wv: rg = wv&3 (W rows l0+rg*4..+3), qt = wv>>2
// (act rows I0..I0+4, I0 = min(qt*4, NR-5)). unit u = (l-tile, k-slab).
template <int NR>
__device__ __forceinline__ void gemv(const float* __restrict__ W,
                                     const float* __restrict__ act,
                                     float* __restrict__ P,
                                     int L, int K, int SLAB) {
    const int lane = threadIdx.x & 63, wv = threadIdx.x >> 6;
    const int rg = wv & 3, qt = wv >> 2;
    const int I0 = (qt * 4 < NR - 5) ? qt * 4 : NR - 5;
    const int LT = L >> 4, NS = K / SLAB, total = LT * NS;
    for (int u = blockIdx.x; u < total; u += gridDim.x) {
        const int lt = u % LT, sx = u / LT;
        const int l0 = lt * 16 + rg * 4;
        const int k0 = sx * SLAB;
        const float* Wp = W + (size_t)l0 * K + k0;
        const float* Ap = act + (size_t)I0 * K + k0;
        float acc[5][4];
#pragma unroll
        for (int j = 0; j < 5; ++j)
#pragma unroll
            for (int r = 0; r < 4; ++r) acc[j][r] = 0.f;
        for (int kk = 0; kk < SLAB; kk += 256) {
            const int idx = kk + lane * 4;
            float4 w4[4], a4[5];
#pragma unroll
            for (int r = 0; r < 4; ++r)
                w4[r] = *reinterpret_cast<const float4*>(Wp + (size_t)r * K + idx);
#pragma unroll
            for (int j = 0; j < 5; ++j)
                a4[j] = *reinterpret_cast<const float4*>(Ap + (size_t)j * K + idx);
#pragma unroll
            for (int j = 0; j < 5; ++j)
#pragma unroll
                for (int r = 0; r < 4; ++r)
                    acc[j][r] += a4[j].x * w4[r].x + a4[j].y * w4[r].y +
                                 a4[j].z * w4[r].z + a4[j].w * w4[r].w;
        }
        // butterfly k-reduce; lane ii*4+r keeps output (I0+ii, l0+rg*4+r)
        float vout = 0.f;
#pragma unroll
        for (int j = 0; j < 5; ++j)
#pragma unroll
            for (int r = 0; r < 4; ++r) {
                float v = acc[j][r];
#pragma unroll
                for (int off = 32; off; off >>= 1) v += __shfl_xor(v, off);
                if (lane == j * 4 + r) vout = v;
            }
        if (lane < 20)
            P[(size_t)sx * NR * L + (size_t)(I0 + (lane >> 2)) * L +
              l0 + (lane & 3)] = vout;
    }
}

// 1024 threads: each owns 2 cols of the 2048-wide row
__device__ __forceinline__ void redln_f(const float* __restrict__ P, int S,
                                        int rowoff, int NRL,
                                        const float* __restrict__ fb,
                                        float* __restrict__ ss,
                                        const float* __restrict__ g,
                                        const float* __restrict__ b,
                                        float* __restrict__ lnout,
                                        float* shred) {
    const int row = blockIdx.x;
    if (row >= 17) return;
    const int tid = threadIdx.x;
    const int base = row * 2048;
    float vv[2];
    float s = 0.f, q = 0.f;
#pragma unroll
    for (int c = 0; c < 2; ++c) {
        int col = tid + c * 1024;
        float xv = ss[base + col];
        if (row >= rowoff) {
            const float* pp = P + (size_t)(row - rowoff) * 2048 + col;
            for (int y = 0; y < S; ++y) xv += pp[(size_t)y * NRL];
        }
        if (fb != nullptr) xv += fb[col];
        ss[base + col] = xv;
        vv[c] = xv;
        s += xv;
        q += xv * xv;
    }
#pragma unroll
    for (int off = 32; off; off >>= 1) {
        s += __shfl_xor(s, off);
        q += __shfl_xor(q, off);
    }
    int wvi = tid >> 6;
    if ((tid & 63) == 0) { shred[wvi] = s; shred[16 + wvi] = q; }
    __syncthreads();
    s = 0.f; q = 0.f;
#pragma unroll
    for (int w = 0; w < 16; ++w) { s += shred[w]; q += shred[16 + w]; }
    float mean = s * (1.f / 2048.f);
    float var = q * (1.f / 2048.f) - mean * mean;
    float rstd = rsqrtf(var + 1e-5f);
#pragma unroll
    for (int c = 0; c < 2; ++c) {
        int col = tid + c * 1024;
        lnout[base + col] = (vv[c] - mean) * rstd * g[col] + b[col];
    }
    __syncthreads();
}

__global__ __launch_bounds__(1024) void mega(
    const float* __restrict__ x, const float* __restrict__ weight,
    const float* __restrict__ bias, const float* __restrict__ cls,
    const float* __restrict__ Wqkv, const float* __restrict__ Wo,
    const float* __restrict__ ln1_g, const float* __restrict__ ln1_b,
    const float* __restrict__ ln2_g, const float* __restrict__ ln2_b,
    const float* __restrict__ ln3_g, const float* __restrict__ ln3_b,
    const float* __restrict__ fc1_w, const float* __restrict__ fc1_b,
    const float* __restrict__ fc2_w, const float* __restrict__ fc2_b,
    float* __restrict__ out, float* __restrict__ ws, unsigned* __restrict__ bar) {
    __shared__ float shred[32];
    unsigned* cnt = bar;
    unsigned* gen = bar + 1;

    float* ss     = ws;                 // 34816
    float* altx   = ws + 34816;         // 32768
    float* imv    = ws + 67584;         // 34816
    float* tbuf   = ws + 102400;        // 139264
    float* ln1buf = ws + 241664;        // 34816
    float* ln2buf = ws + 276480;        // 34816
    float* Pq     = ws + 311296;        // 417792 (max: qkv 2x17x6144)
    float* Pf     = ws + 729088;        // 139264 (fc1 1 plane)

    // ---- phase 0: init ss = bias (+cls), altx ----
    for (int idx = blockIdx.x * 1024 + threadIdx.x; idx < 17 * 2048;
         idx += gridDim.x * 1024) {
        int r = idx >> 11, m = idx & 2047;
        float v = bias[idx];
        if (r == 0) v += cls[m];
        ss[idx] = v;
        if (idx < 16 * 2048) {
            int i = idx >> 11;
            int c1 = m >> 6, c2 = m & 63;
            const float* p = x + (size_t)(c2 * 32 + c1) * 160 + i * 10;
            float s = 0.f;
#pragma unroll
            for (int j = 0; j < 10; ++j) s += p[j];
            altx[idx] = s * 0.1f;
        }
    }
    gbar(cnt, gen);

    // ---- GEMM1: ss[1:17] += altx @ weight.T (2 planes [16][2048]) ----
    gemv<16>(weight, altx, Pq, 2048, 2048, 1024);
    gbar(cnt, gen);
    redln_f(Pq, 2, 1, 32768, nullptr, ss, ln1_g, ln1_b, ln1buf, shred);
    gbar(cnt, gen);

    for (int k = 0; k < 4; ++k) {
        // qkv (2 planes [17][6144])
        gemv<17>(Wqkv + (size_t)k * 12582912, ln1buf, Pq, 6144, 2048, 1024);
        gbar(cnt, gen);
        // attn: blocks 0..15, first wave only; sums 2 planes inline
        if (blockIdx.x < 16 && threadIdx.x < 64) {
            const int h = blockIdx.x, lane = threadIdx.x;
            const float scale = 0.08838834764831845f;
            float run0 = 0.f, run1 = 0.f;
            for (int i = 0; i < 17; ++i) {
                const size_t idx = (size_t)i * 6144 + h * 128;
                float q0 = 0.f, q1 = 0.f, k0 = 0.f, k1 = 0.f, v0 = 0.f, v1 = 0.f;
#pragma unroll
                for (int s = 0; s < 2; ++s) {
                    const float* base = Pq + (size_t)s * 104448 + idx;
                    q0 += base[lane];        q1 += base[lane + 64];
                    k0 += base[2048 + lane]; k1 += base[2048 + lane + 64];
                    v0 += base[4096 + lane]; v1 += base[4096 + lane + 64];
                }
                float p = q0 * k0 + q1 * k1;
#pragma unroll
                for (int off = 32; off; off >>= 1) p += __shfl_xor(p, off);
                float rsa = p * scale;
                float iv0 = rsa * v0, iv1 = rsa * v1;
                float o0, o1;
                if (i < 16) { run0 += iv0; run1 += iv1; o0 = run0; o1 = run1; }
                else        { o0 = iv0; o1 = iv1; }
                imv[(size_t)i * 2048 + h * 128 + lane] = o0;
                imv[(size_t)i * 2048 + h * 128 + lane + 64] = o1;
            }
        }
        gbar(cnt, gen);
        // Wo (2 planes [17][2048])
        gemv<17>(Wo + (size_t)k * 4194304, imv, Pq, 2048, 2048, 1024);
        gbar(cnt, gen);
        redln_f(Pq, 2, 0, 34816, nullptr, ss, ln2_g, ln2_b, ln2buf, shred);
        gbar(cnt, gen);
        // fc1 (1 plane [17][8192], raw)
        gemv<17>(fc1_w, ln2buf, Pf, 8192, 2048, 2048);
        gbar(cnt, gen);
        // gelu: tbuf = gelu(Pf + fc1_b)
        for (int idx = blockIdx.x * 1024 + threadIdx.x; idx < 139264;
             idx += gridDim.x * 1024) {
            float s = fc1_b[idx & 8191] + Pf[idx];
            tbuf[idx] = 0.5f * s * (1.f + erff(s * 0.70710678f));
        }
        gbar(cnt, gen);
        // fc2 (2 planes [17][2048])
        gemv<17>(fc2_w, tbuf, Pq, 2048, 8192, 4096);
        gbar(cnt, gen);
        if (k < 3)
            redln_f(Pq, 2, 0, 34816, fc2_b, ss, ln1_g, ln1_b, ln1buf, shred);
        else
            redln_f(Pq, 2, 0, 34816, fc2_b, ss, ln3_g, ln3_b, out, shred);
        gbar(cnt, gen);
    }
}

extern "C" void kernel_launch(void* const* d_in, const int* in_sizes, int n_in,
                              void* d_out, int out_size, void* d_ws, size_t ws_size,
                              hipStream_t stream) {
    const float* x      = (const float*)d_in[0];
    const float* weight = (const float*)d_in[1];
    const float* bias   = (const float*)d_in[2];
    const float* cls    = (const float*)d_in[3];
    const float* Wqkv   = (const float*)d_in[4];
    const float* Wo     = (const float*)d_in[5];
    const float* ln1_g  = (const float*)d_in[6];
    const float* ln1_b  = (const float*)d_in[7];
    const float* ln2_g  = (const float*)d_in[8];
    const float* ln2_b  = (const float*)d_in[9];
    const float* ln3_g  = (const float*)d_in[10];
    const float* ln3_b  = (const float*)d_in[11];
    const float* fc1_w  = (const float*)d_in[12];
    const float* fc1_b  = (const float*)d_in[13];
    const float* fc2_w  = (const float*)d_in[14];
    const float* fc2_b  = (const float*)d_in[15];
    float* out = (float*)d_out;
    float* ws  = (float*)d_ws;
    unsigned* bar = (unsigned*)(ws + 1007616);

    hipMemsetAsync(bar, 0, 8, stream);
    mega<<<256, 1024, 0, stream>>>(x, weight, bias, cls, Wqkv, Wo,
                                   ln1_g, ln1_b, ln2_g, ln2_b, ln3_g, ln3_b,
                                   fc1_w, fc1_b, fc2_w, fc2_b, out, ws, bar);
}

// Round 14
// 1295.532 us; speedup vs baseline: 2.1577x; 1.0761x over previous
//
#include <hip/hip_runtime.h>
#include <math.h>

// One persistent kernel, 256 blocks x 512 thr (8 waves).
// RESIDENCY LAW (R10/R13 deadlocks): grid must be <= 256 blocks — a 512-thr
// block is schedulable at any VGPR<=256, and 256 blocks <= 256 CUs => all
// resident regardless of allocator choice => grid barrier safe.
// SPILL LAW (R9/R11/R12): body must fit the allocator's pick (64-128);
// low-pressure gemv: wave = (rg in 0..1 -> 4 W rows) x (qt in 0..3 -> 5 act
// rows, boundary rows duplicated, bitwise-identical double-writes);
// acc[5][4] + 9 staged float4 ~= 85 VGPR -> fits 128.
// k-split planes P[s][i][l]; init/attn/redln/gelu inline between barriers.

#define AGENT __HIP_MEMORY_SCOPE_AGENT

__device__ __forceinline__ unsigned aload(unsigned* p) {
    return __hip_atomic_load(p, __ATOMIC_RELAXED, AGENT);
}

__device__ __forceinline__ void gbar(unsigned* cnt, unsigned* gen) {
    __syncthreads();
    if (threadIdx.x == 0) {
        __threadfence();
        unsigned g = aload(gen);
        unsigned arrived =
            __hip_atomic_fetch_add(cnt, 1u, __ATOMIC_ACQ_REL, AGENT) + 1;
        if (arrived == gridDim.x) {
            __hip_atomic_store(cnt, 0u, __ATOMIC_RELAXED, AGENT);
            __hip_atomic_fetch_add(gen, 1u, __ATOMIC_ACQ_REL, AGENT);
        } else {
            while (aload(gen) == g) __builtin_amdgcn_s_sleep(2);
        }
        __threadfence();
    }
    __syncthreads();
}

// block: 8 waves; wave wv: rg = wv&1 (W rows l0+rg*4..+3), qt = wv>>1
// (act rows I0..I0+4, I0 = min(qt*4, NR-5)). unit u = (l-tile of 8, k-slab).
template <int NR>
__device__ __forceinline__ void gemv(const float* __restrict__ W,
                                     const float* __restrict__ act,
                                     float* __restrict__ P,
                                     int L, int K, int SLAB) {
    const int lane = threadIdx.x & 63, wv = threadIdx.x >> 6;
    const int rg = wv & 1, qt = wv >> 1;
    const int I0 = (qt * 4 < NR - 5) ? qt * 4 : NR - 5;
    const int LT = L >> 3, NS = K / SLAB, total = LT * NS;
    for (int u = blockIdx.x; u < total; u += gridDim.x) {
        const int lt = u % LT, sx = u / LT;
        const int l0 = lt * 8 + rg * 4;
        const int k0 = sx * SLAB;
        const float* Wp = W + (size_t)l0 * K + k0;
        const float* Ap = act + (size_t)I0 * K + k0;
        float acc[5][4];
#pragma unroll
        for (int j = 0; j < 5; ++j)
#pragma unroll
            for (int r = 0; r < 4; ++r) acc[j][r] = 0.f;
        for (int kk = 0; kk < SLAB; kk += 256) {
            const int idx = kk + lane * 4;
            float4 w4[4], a4[5];
#pragma unroll
            for (int r = 0; r < 4; ++r)
                w4[r] = *reinterpret_cast<const float4*>(Wp + (size_t)r * K + idx);
#pragma unroll
            for (int j = 0; j < 5; ++j)
                a4[j] = *reinterpret_cast<const float4*>(Ap + (size_t)j * K + idx);
#pragma unroll
            for (int j = 0; j < 5; ++j)
#pragma unroll
                for (int r = 0; r < 4; ++r)
                    acc[j][r] += a4[j].x * w4[r].x + a4[j].y * w4[r].y +
                                 a4[j].z * w4[r].z + a4[j].w * w4[r].w;
        }
        // butterfly k-reduce; lane j*4+r keeps output (I0+j, l0+r)
        float vout = 0.f;
#pragma unroll
        for (int j = 0; j < 5; ++j)
#pragma unroll
            for (int r = 0; r < 4; ++r) {
                float v = acc[j][r];
#pragma unroll
                for (int off = 32; off; off >>= 1) v += __shfl_xor(v, off);
                if (lane == j * 4 + r) vout = v;
            }
        if (lane < 20)
            P[(size_t)sx * NR * L + (size_t)(I0 + (lane >> 2)) * L +
              l0 + (lane & 3)] = vout;
    }
}

// 512 threads: each owns 4 cols of the 2048-wide row
__device__ __forceinline__ void redln_f(const float* __restrict__ P, int S,
                                        int rowoff, int NRL,
                                        const float* __restrict__ fb,
                                        float* __restrict__ ss,
                                        const float* __restrict__ g,
                                        const float* __restrict__ b,
                                        float* __restrict__ lnout,
                                        float* shred) {
    const int row = blockIdx.x;
    if (row >= 17) return;
    const int tid = threadIdx.x;
    const int base = row * 2048;
    float vv[4];
    float s = 0.f, q = 0.f;
#pragma unroll
    for (int c = 0; c < 4; ++c) {
        int col = tid + c * 512;
        float xv = ss[base + col];
        if (row >= rowoff) {
            const float* pp = P + (size_t)(row - rowoff) * 2048 + col;
            for (int y = 0; y < S; ++y) xv += pp[(size_t)y * NRL];
        }
        if (fb != nullptr) xv += fb[col];
        ss[base + col] = xv;
        vv[c] = xv;
        s += xv;
        q += xv * xv;
    }
#pragma unroll
    for (int off = 32; off; off >>= 1) {
        s += __shfl_xor(s, off);
        q += __shfl_xor(q, off);
    }
    int wvi = tid >> 6;
    if ((tid & 63) == 0) { shred[wvi] = s; shred[8 + wvi] = q; }
    __syncthreads();
    s = 0.f; q = 0.f;
#pragma unroll
    for (int w = 0; w < 8; ++w) { s += shred[w]; q += shred[8 + w]; }
    float mean = s * (1.f / 2048.f);
    float var = q * (1.f / 2048.f) - mean * mean;
    float rstd = rsqrtf(var + 1e-5f);
#pragma unroll
    for (int c = 0; c < 4; ++c) {
        int col = tid + c * 512;
        lnout[base + col] = (vv[c] - mean) * rstd * g[col] + b[col];
    }
    __syncthreads();
}

__global__ __launch_bounds__(512) void mega(
    const float* __restrict__ x, const float* __restrict__ weight,
    const float* __restrict__ bias, const float* __restrict__ cls,
    const float* __restrict__ Wqkv, const float* __restrict__ Wo,
    const float* __restrict__ ln1_g, const float* __restrict__ ln1_b,
    const float* __restrict__ ln2_g, const float* __restrict__ ln2_b,
    const float* __restrict__ ln3_g, const float* __restrict__ ln3_b,
    const float* __restrict__ fc1_w, const float* __restrict__ fc1_b,
    const float* __restrict__ fc2_w, const float* __restrict__ fc2_b,
    float* __restrict__ out, float* __restrict__ ws, unsigned* __restrict__ bar) {
    __shared__ float shred[16];
    unsigned* cnt = bar;
    unsigned* gen = bar + 1;

    float* ss     = ws;                 // 34816
    float* altx   = ws + 34816;         // 32768
    float* imv    = ws + 67584;         // 34816
    float* tbuf   = ws + 102400;        // 139264
    float* ln1buf = ws + 241664;        // 34816
    float* ln2buf = ws + 276480;        // 34816
    float* Pq     = ws + 311296;        // 417792 (max: qkv 2x17x6144)
    float* Pf     = ws + 729088;        // 139264 (fc1 1 plane)

    // ---- phase 0: init ss = bias (+cls), altx ----
    for (int idx = blockIdx.x * 512 + threadIdx.x; idx < 17 * 2048;
         idx += gridDim.x * 512) {
        int r = idx >> 11, m = idx & 2047;
        float v = bias[idx];
        if (r == 0) v += cls[m];
        ss[idx] = v;
        if (idx < 16 * 2048) {
            int i = idx >> 11;
            int c1 = m >> 6, c2 = m & 63;
            const float* p = x + (size_t)(c2 * 32 + c1) * 160 + i * 10;
            float s = 0.f;
#pragma unroll
            for (int j = 0; j < 10; ++j) s += p[j];
            altx[idx] = s * 0.1f;
        }
    }
    gbar(cnt, gen);

    // ---- GEMM1: ss[1:17] += altx @ weight.T (2 planes [16][2048]) ----
    gemv<16>(weight, altx, Pq, 2048, 2048, 1024);
    gbar(cnt, gen);
    redln_f(Pq, 2, 1, 32768, nullptr, ss, ln1_g, ln1_b, ln1buf, shred);
    gbar(cnt, gen);

    for (int k = 0; k < 4; ++k) {
        // qkv (2 planes [17][6144])
        gemv<17>(Wqkv + (size_t)k * 12582912, ln1buf, Pq, 6144, 2048, 1024);
        gbar(cnt, gen);
        // attn: blocks 0..15, first wave only; sums 2 planes inline
        if (blockIdx.x < 16 && threadIdx.x < 64) {
            const int h = blockIdx.x, lane = threadIdx.x;
            const float scale = 0.08838834764831845f;
            float run0 = 0.f, run1 = 0.f;
            for (int i = 0; i < 17; ++i) {
                const size_t idx = (size_t)i * 6144 + h * 128;
                float q0 = 0.f, q1 = 0.f, k0 = 0.f, k1 = 0.f, v0 = 0.f, v1 = 0.f;
#pragma unroll
                for (int s = 0; s < 2; ++s) {
                    const float* base = Pq + (size_t)s * 104448 + idx;
                    q0 += base[lane];        q1 += base[lane + 64];
                    k0 += base[2048 + lane]; k1 += base[2048 + lane + 64];
                    v0 += base[4096 + lane]; v1 += base[4096 + lane + 64];
                }
                float p = q0 * k0 + q1 * k1;
#pragma unroll
                for (int off = 32; off; off >>= 1) p += __shfl_xor(p, off);
                float rsa = p * scale;
                float iv0 = rsa * v0, iv1 = rsa * v1;
                float o0, o1;
                if (i < 16) { run0 += iv0; run1 += iv1; o0 = run0; o1 = run1; }
                else        { o0 = iv0; o1 = iv1; }
                imv[(size_t)i * 2048 + h * 128 + lane] = o0;
                imv[(size_t)i * 2048 + h * 128 + lane + 64] = o1;
            }
        }
        gbar(cnt, gen);
        // Wo (2 planes [17][2048])
        gemv<17>(Wo + (size_t)k * 4194304, imv, Pq, 2048, 2048, 1024);
        gbar(cnt, gen);
        redln_f(Pq, 2, 0, 34816, nullptr, ss, ln2_g, ln2_b, ln2buf, shred);
        gbar(cnt, gen);
        // fc1 (1 plane [17][8192], raw)
        gemv<17>(fc1_w, ln2buf, Pf, 8192, 2048, 2048);
        gbar(cnt, gen);
        // gelu: tbuf = gelu(Pf + fc1_b)
        for (int idx = blockIdx.x * 512 + threadIdx.x; idx < 139264;
             idx += gridDim.x * 512) {
            float s = fc1_b[idx & 8191] + Pf[idx];
            tbuf[idx] = 0.5f * s * (1.f + erff(s * 0.70710678f));
        }
        gbar(cnt, gen);
        // fc2 (2 planes [17][2048])
        gemv<17>(fc2_w, tbuf, Pq, 2048, 8192, 4096);
        gbar(cnt, gen);
        if (k < 3)
            redln_f(Pq, 2, 0, 34816, fc2_b, ss, ln1_g, ln1_b, ln1buf, shred);
        else
            redln_f(Pq, 2, 0, 34816, fc2_b, ss, ln3_g, ln3_b, out, shred);
        gbar(cnt, gen);
    }
}

extern "C" void kernel_launch(void* const* d_in, const int* in_sizes, int n_in,
                              void* d_out, int out_size, void* d_ws, size_t ws_size,
                              hipStream_t stream) {
    const float* x      = (const float*)d_in[0];
    const float* weight = (const float*)d_in[1];
    const float* bias   = (const float*)d_in[2];
    const float* cls    = (const float*)d_in[3];
    const float* Wqkv   = (const float*)d_in[4];
    const float* Wo     = (const float*)d_in[5];
    const float* ln1_g  = (const float*)d_in[6];
    const float* ln1_b  = (const float*)d_in[7];
    const float* ln2_g  = (const float*)d_in[8];
    const float* ln2_b  = (const float*)d_in[9];
    const float* ln3_g  = (const float*)d_in[10];
    const float* ln3_b  = (const float*)d_in[11];
    const float* fc1_w  = (const float*)d_in[12];
    const float* fc1_b  = (const float*)d_in[13];
    const float* fc2_w  = (const float*)d_in[14];
    const float* fc2_b  = (const float*)d_in[15];
    float* out = (float*)d_out;
    float* ws  = (float*)d_ws;
    unsigned* bar = (unsigned*)(ws + 1007616);

    hipMemsetAsync(bar, 0, 8, stream);
    mega<<<256, 512, 0, stream>>>(x, weight, bias, cls, Wqkv, Wo,
                                  ln1_g, ln1_b, ln2_g, ln2_b, ln3_g, ln3_b,
                                  fc1_w, fc1_b, fc2_w, fc2_b, out, ws, bar);
}

// Round 15
// 503.117 us; speedup vs baseline: 5.5562x; 2.5750x over previous
//
#include <hip/hip_runtime.h>
#include <math.h>

// Multi-kernel (R5 structure, best=581us) + no-spill gemv body (R14-proven
// @128 VGPR) + register weight-prefetch + big grids for TLP. No grid barrier.
// gemvP: block = 256 thr = 4 waves, owns 4 consecutive W rows; wave qt covers
// act rows I0..I0+4 (I0 = min(4*qt, NR-5); boundary rows duplicated,
// bitwise-identical double-writes). SLAB = 2048 cols, 8 chunks of 256; per
// chunk: issue 5 act float4 (L2-hot), issue next chunk's 4 weight float4
// (HBM prefetch), then 80 FMA on current regs. Butterfly k-reduce in wave.
// S k-split planes (fc2 only); consumers (attn/gelu/redln) sum planes.

__global__ void k0_init(const float* __restrict__ x,
                        const float* __restrict__ bias,
                        const float* __restrict__ cls,
                        float* __restrict__ ss,
                        float* __restrict__ altx) {
    int idx = blockIdx.x * 256 + threadIdx.x;
    if (idx < 17 * 2048) {
        int r = idx >> 11, m = idx & 2047;
        float v = bias[idx];
        if (r == 0) v += cls[m];
        ss[idx] = v;
    }
    if (idx < 16 * 2048) {
        int i = idx >> 11, m = idx & 2047;
        int c1 = m >> 6, c2 = m & 63;
        const float* p = x + (size_t)(c2 * 32 + c1) * 160 + i * 10;
        float s = 0.f;
#pragma unroll
        for (int j = 0; j < 10; ++j) s += p[j];
        altx[idx] = s * 0.1f;
    }
}

// grid (L/4, S); k0 = blockIdx.y*2048. out[i,l] = sum_m act[i,m]*W[l,m].
template <int NR>
__global__ __launch_bounds__(256, 4) void gemvP(
    const float* __restrict__ W, const float* __restrict__ act,
    float* __restrict__ P, int L, int K) {
    const int lane = threadIdx.x & 63;
    const int qt = threadIdx.x >> 6;
    const int I0 = (qt * 4 < NR - 5) ? qt * 4 : NR - 5;
    const int l0 = blockIdx.x * 4;
    const int k0 = blockIdx.y * 2048;
    const float* Wp = W + (size_t)l0 * K + k0 + lane * 4;
    const float* Ap = act + (size_t)I0 * K + k0 + lane * 4;

    float acc[5][4];
#pragma unroll
    for (int j = 0; j < 5; ++j)
#pragma unroll
        for (int r = 0; r < 4; ++r) acc[j][r] = 0.f;

    float4 w4[4], wn[4];
#pragma unroll
    for (int r = 0; r < 4; ++r)
        w4[r] = *reinterpret_cast<const float4*>(Wp + (size_t)r * K);

    for (int c = 0; c < 8; ++c) {
        float4 a4[5];
#pragma unroll
        for (int j = 0; j < 5; ++j)
            a4[j] = *reinterpret_cast<const float4*>(Ap + (size_t)j * K + c * 256);
        if (c < 7) {
#pragma unroll
            for (int r = 0; r < 4; ++r)
                wn[r] = *reinterpret_cast<const float4*>(
                    Wp + (size_t)r * K + (c + 1) * 256);
        }
#pragma unroll
        for (int j = 0; j < 5; ++j)
#pragma unroll
            for (int r = 0; r < 4; ++r)
                acc[j][r] += a4[j].x * w4[r].x + a4[j].y * w4[r].y +
                             a4[j].z * w4[r].z + a4[j].w * w4[r].w;
#pragma unroll
        for (int r = 0; r < 4; ++r) w4[r] = wn[r];
    }

    // butterfly k-reduce; lane j*4+r keeps output (I0+j, l0+r)
    float vout = 0.f;
#pragma unroll
    for (int j = 0; j < 5; ++j)
#pragma unroll
        for (int r = 0; r < 4; ++r) {
            float v = acc[j][r];
#pragma unroll
            for (int off = 32; off; off >>= 1) v += __shfl_xor(v, off);
            if (lane == j * 4 + r) vout = v;
        }
    if (lane < 20)
        P[(size_t)blockIdx.y * NR * L + (size_t)(I0 + (lane >> 2)) * L +
          l0 + (lane & 3)] = vout;
}

// tbuf = gelu(Pf + fc1_b)
__global__ void red_gelu(const float* __restrict__ Pf, const float* __restrict__ fb,
                         float* __restrict__ out) {
    int idx = blockIdx.x * 256 + threadIdx.x;
    float s = fb[idx & 8191] + Pf[idx];
    out[idx] = 0.5f * s * (1.f + erff(s * 0.70710678f));
}

// one block per row: ss[row] += sum_S P[row] (+fb); lnout = LN(ss)*g+b
__global__ void redln(const float* __restrict__ P, int S, int rowoff, int NRL,
                      const float* __restrict__ fb, float* __restrict__ ss,
                      const float* __restrict__ g, const float* __restrict__ b,
                      float* __restrict__ lnout) {
    const int row = blockIdx.x;
    const int tid = threadIdx.x;
    const int base = row * 2048;
    float vv[8];
    float s = 0.f, q = 0.f;
#pragma unroll
    for (int c = 0; c < 8; ++c) {
        int col = tid + c * 256;
        float xv = ss[base + col];
        if (row >= rowoff) {
            const float* pp = P + (size_t)(row - rowoff) * 2048 + col;
            for (int y = 0; y < S; ++y) xv += pp[(size_t)y * NRL];
        }
        if (fb != nullptr) xv += fb[col];
        ss[base + col] = xv;
        vv[c] = xv;
        s += xv;
        q += xv * xv;
    }
#pragma unroll
    for (int off = 32; off; off >>= 1) {
        s += __shfl_xor(s, off);
        q += __shfl_xor(q, off);
    }
    __shared__ float red[8];
    int wvi = tid >> 6;
    if ((tid & 63) == 0) { red[wvi] = s; red[4 + wvi] = q; }
    __syncthreads();
    s = red[0] + red[1] + red[2] + red[3];
    q = red[4] + red[5] + red[6] + red[7];
    float mean = s * (1.f / 2048.f);
    float var = q * (1.f / 2048.f) - mean * mean;
    float rstd = rsqrtf(var + 1e-5f);
#pragma unroll
    for (int c = 0; c < 8; ++c) {
        int col = tid + c * 256;
        lnout[base + col] = (vv[c] - mean) * rstd * g[col] + b[col];
    }
}

// one block per head; 64 threads; reads qkv directly
__global__ void attn_kernel(const float* __restrict__ qkv, float* __restrict__ imv) {
    int h = blockIdx.x, lane = threadIdx.x;
    const float scale = 0.08838834764831845f;  // 1/sqrt(128)
    float run0 = 0.f, run1 = 0.f;
    for (int i = 0; i < 17; ++i) {
        const float* base = qkv + (size_t)i * 6144 + h * 128;
        float q0 = base[lane], q1 = base[lane + 64];
        float k0 = base[2048 + lane], k1 = base[2048 + lane + 64];
        float v0 = base[4096 + lane], v1 = base[4096 + lane + 64];
        float p = q0 * k0 + q1 * k1;
#pragma unroll
        for (int off = 32; off; off >>= 1) p += __shfl_xor(p, off);
        float rsa = p * scale;
        float iv0 = rsa * v0, iv1 = rsa * v1;
        float o0, o1;
        if (i < 16) { run0 += iv0; run1 += iv1; o0 = run0; o1 = run1; }
        else        { o0 = iv0; o1 = iv1; }
        imv[(size_t)i * 2048 + h * 128 + lane] = o0;
        imv[(size_t)i * 2048 + h * 128 + lane + 64] = o1;
    }
}

extern "C" void kernel_launch(void* const* d_in, const int* in_sizes, int n_in,
                              void* d_out, int out_size, void* d_ws, size_t ws_size,
                              hipStream_t stream) {
    const float* x      = (const float*)d_in[0];
    const float* weight = (const float*)d_in[1];
    const float* bias   = (const float*)d_in[2];
    const float* cls    = (const float*)d_in[3];
    const float* Wqkv   = (const float*)d_in[4];
    const float* Wo     = (const float*)d_in[5];
    const float* ln1_g  = (const float*)d_in[6];
    const float* ln1_b  = (const float*)d_in[7];
    const float* ln2_g  = (const float*)d_in[8];
    const float* ln2_b  = (const float*)d_in[9];
    const float* ln3_g  = (const float*)d_in[10];
    const float* ln3_b  = (const float*)d_in[11];
    const float* fc1_w  = (const float*)d_in[12];
    const float* fc1_b  = (const float*)d_in[13];
    const float* fc2_w  = (const float*)d_in[14];
    const float* fc2_b  = (const float*)d_in[15];
    float* out = (float*)d_out;

    float* ws     = (float*)d_ws;
    float* ss     = ws;                  // 34816
    float* altx   = ws + 34816;          // 32768
    float* imv    = ws + 67584;          // 34816
    float* qkv    = ws + 102400;         // 104448
    float* Pf     = ws + 206848;         // 139264 (fc1 raw)
    float* tbuf   = ws + 346112;         // 139264 (gelu out)
    float* ln1buf = ws + 485376;         // 34816
    float* ln2buf = ws + 520192;         // 34816
    float* Pg     = ws + 555008;         // 139264 (gemm1 1 plane / fc2 4 planes)

    k0_init<<<136, 256, 0, stream>>>(x, bias, cls, ss, altx);
    // ss[1:17] += altx @ weight.T  (1 plane [16][2048])
    gemvP<16><<<dim3(512, 1), 256, 0, stream>>>(weight, altx, Pg, 2048, 2048);
    redln<<<17, 256, 0, stream>>>(Pg, 1, 1, 32768, nullptr, ss, ln1_g, ln1_b, ln1buf);

    for (int k = 0; k < 4; ++k) {
        // qkv = Wqkv[k] @ ln1buf  (direct, L=6144)
        gemvP<17><<<dim3(1536, 1), 256, 0, stream>>>(
            Wqkv + (size_t)k * 12582912, ln1buf, qkv, 6144, 2048);
        attn_kernel<<<16, 64, 0, stream>>>(qkv, imv);
        // Pg = imv @ Wo[k].T  (1 plane [17][2048])
        gemvP<17><<<dim3(512, 1), 256, 0, stream>>>(
            Wo + (size_t)k * 4194304, imv, Pg, 2048, 2048);
        redln<<<17, 256, 0, stream>>>(Pg, 1, 0, 34816, nullptr, ss, ln2_g, ln2_b, ln2buf);
        // Pf = fc1_w @ ln2buf  (direct raw, L=8192)
        gemvP<17><<<dim3(2048, 1), 256, 0, stream>>>(fc1_w, ln2buf, Pf, 8192, 2048);
        red_gelu<<<544, 256, 0, stream>>>(Pf, fc1_b, tbuf);
        // Pg = fc2_w @ tbuf  (4 planes [17][2048], K=8192)
        gemvP<17><<<dim3(512, 4), 256, 0, stream>>>(fc2_w, tbuf, Pg, 2048, 8192);
        if (k < 3)
            redln<<<17, 256, 0, stream>>>(Pg, 4, 0, 34816, fc2_b, ss, ln1_g, ln1_b, ln1buf);
        else
            redln<<<17, 256, 0, stream>>>(Pg, 4, 0, 34816, fc2_b, ss, ln3_g, ln3_b, out);
    }
}

// Round 16
// 473.470 us; speedup vs baseline: 5.9041x; 1.0626x over previous
//
#include <hip/hip_runtime.h>
#include <math.h>

// R15 (503us, best) + 2-deep weight prefetch + k-split for small GEMMs.
// gemvP<NR,CH>: block = 256 thr = 4 waves, owns 4 consecutive W rows; wave qt
// covers act rows I0..I0+4 (I0 = min(4*qt, NR-5); boundary rows duplicated,
// bitwise-identical double-writes). Slab = CH*256 cols. Weight registers
// w0/w1/w2 = 3-set rotation (2 chunks in flight) so HBM latency (~900cyc) is
// covered by 2 x 4waves x 160cyc. acc20+w48+a20 ~= 88 live VGPR -> fits the
// 128 cap of launch_bounds(256,4) (R14/R15 proven no-spill regime).
// S k-split planes; consumers (attn/gelu/redln) sum planes.

__global__ void k0_init(const float* __restrict__ x,
                        const float* __restrict__ bias,
                        const float* __restrict__ cls,
                        float* __restrict__ ss,
                        float* __restrict__ altx) {
    int idx = blockIdx.x * 256 + threadIdx.x;
    if (idx < 17 * 2048) {
        int r = idx >> 11, m = idx & 2047;
        float v = bias[idx];
        if (r == 0) v += cls[m];
        ss[idx] = v;
    }
    if (idx < 16 * 2048) {
        int i = idx >> 11, m = idx & 2047;
        int c1 = m >> 6, c2 = m & 63;
        const float* p = x + (size_t)(c2 * 32 + c1) * 160 + i * 10;
        float s = 0.f;
#pragma unroll
        for (int j = 0; j < 10; ++j) s += p[j];
        altx[idx] = s * 0.1f;
    }
}

// grid (L/4, S); slab = CH*256; out[i,l] = sum_m act[i,m]*W[l,m]
template <int NR, int CH>
__global__ __launch_bounds__(256, 4) void gemvP(
    const float* __restrict__ W, const float* __restrict__ act,
    float* __restrict__ P, int L, int K) {
    const int lane = threadIdx.x & 63;
    const int qt = threadIdx.x >> 6;
    const int I0 = (qt * 4 < NR - 5) ? qt * 4 : NR - 5;
    const int l0 = blockIdx.x * 4;
    const int k0 = blockIdx.y * (CH * 256);
    const float* Wp = W + (size_t)l0 * K + k0 + lane * 4;
    const float* Ap = act + (size_t)I0 * K + k0 + lane * 4;

    float acc[5][4];
#pragma unroll
    for (int j = 0; j < 5; ++j)
#pragma unroll
        for (int r = 0; r < 4; ++r) acc[j][r] = 0.f;

    float4 w0[4], w1[4], w2[4];
#pragma unroll
    for (int r = 0; r < 4; ++r)
        w0[r] = *reinterpret_cast<const float4*>(Wp + (size_t)r * K);
#pragma unroll
    for (int r = 0; r < 4; ++r)
        w1[r] = *reinterpret_cast<const float4*>(Wp + (size_t)r * K + 256);
#pragma unroll
    for (int r = 0; r < 4; ++r)
        w2[r] = *reinterpret_cast<const float4*>(Wp + (size_t)r * K + 512);

#pragma unroll
    for (int c = 0; c < CH; ++c) {
        float4 a4[5];
#pragma unroll
        for (int j = 0; j < 5; ++j)
            a4[j] = *reinterpret_cast<const float4*>(Ap + (size_t)j * K + c * 256);
#pragma unroll
        for (int j = 0; j < 5; ++j)
#pragma unroll
            for (int r = 0; r < 4; ++r)
                acc[j][r] += a4[j].x * w0[r].x + a4[j].y * w0[r].y +
                             a4[j].z * w0[r].z + a4[j].w * w0[r].w;
#pragma unroll
        for (int r = 0; r < 4; ++r) w0[r] = w1[r];
#pragma unroll
        for (int r = 0; r < 4; ++r) w1[r] = w2[r];
        if (c + 3 < CH) {
#pragma unroll
            for (int r = 0; r < 4; ++r)
                w2[r] = *reinterpret_cast<const float4*>(
                    Wp + (size_t)r * K + (c + 3) * 256);
        }
    }

    // butterfly k-reduce; lane j*4+r keeps output (I0+j, l0+r)
    float vout = 0.f;
#pragma unroll
    for (int j = 0; j < 5; ++j)
#pragma unroll
        for (int r = 0; r < 4; ++r) {
            float v = acc[j][r];
#pragma unroll
            for (int off = 32; off; off >>= 1) v += __shfl_xor(v, off);
            if (lane == j * 4 + r) vout = v;
        }
    if (lane < 20)
        P[(size_t)blockIdx.y * NR * L + (size_t)(I0 + (lane >> 2)) * L +
          l0 + (lane & 3)] = vout;
}

// tbuf = gelu(Pf + fc1_b)
__global__ void red_gelu(const float* __restrict__ Pf, const float* __restrict__ fb,
                         float* __restrict__ out) {
    int idx = blockIdx.x * 256 + threadIdx.x;
    float s = fb[idx & 8191] + Pf[idx];
    out[idx] = 0.5f * s * (1.f + erff(s * 0.70710678f));
}

// one block per row: ss[row] += sum_S P[row] (+fb); lnout = LN(ss)*g+b
__global__ void redln(const float* __restrict__ P, int S, int rowoff, int NRL,
                      const float* __restrict__ fb, float* __restrict__ ss,
                      const float* __restrict__ g, const float* __restrict__ b,
                      float* __restrict__ lnout) {
    const int row = blockIdx.x;
    const int tid = threadIdx.x;
    const int base = row * 2048;
    float vv[8];
    float s = 0.f, q = 0.f;
#pragma unroll
    for (int c = 0; c < 8; ++c) {
        int col = tid + c * 256;
        float xv = ss[base + col];
        if (row >= rowoff) {
            const float* pp = P + (size_t)(row - rowoff) * 2048 + col;
            for (int y = 0; y < S; ++y) xv += pp[(size_t)y * NRL];
        }
        if (fb != nullptr) xv += fb[col];
        ss[base + col] = xv;
        vv[c] = xv;
        s += xv;
        q += xv * xv;
    }
#pragma unroll
    for (int off = 32; off; off >>= 1) {
        s += __shfl_xor(s, off);
        q += __shfl_xor(q, off);
    }
    __shared__ float red[8];
    int wvi = tid >> 6;
    if ((tid & 63) == 0) { red[wvi] = s; red[4 + wvi] = q; }
    __syncthreads();
    s = red[0] + red[1] + red[2] + red[3];
    q = red[4] + red[5] + red[6] + red[7];
    float mean = s * (1.f / 2048.f);
    float var = q * (1.f / 2048.f) - mean * mean;
    float rstd = rsqrtf(var + 1e-5f);
#pragma unroll
    for (int c = 0; c < 8; ++c) {
        int col = tid + c * 256;
        lnout[base + col] = (vv[c] - mean) * rstd * g[col] + b[col];
    }
}

// one block per head; 64 threads; reads qkv directly
__global__ void attn_kernel(const float* __restrict__ qkv, float* __restrict__ imv) {
    int h = blockIdx.x, lane = threadIdx.x;
    const float scale = 0.08838834764831845f;  // 1/sqrt(128)
    float run0 = 0.f, run1 = 0.f;
    for (int i = 0; i < 17; ++i) {
        const float* base = qkv + (size_t)i * 6144 + h * 128;
        float q0 = base[lane], q1 = base[lane + 64];
        float k0 = base[2048 + lane], k1 = base[2048 + lane + 64];
        float v0 = base[4096 + lane], v1 = base[4096 + lane + 64];
        float p = q0 * k0 + q1 * k1;
#pragma unroll
        for (int off = 32; off; off >>= 1) p += __shfl_xor(p, off);
        float rsa = p * scale;
        float iv0 = rsa * v0, iv1 = rsa * v1;
        float o0, o1;
        if (i < 16) { run0 += iv0; run1 += iv1; o0 = run0; o1 = run1; }
        else        { o0 = iv0; o1 = iv1; }
        imv[(size_t)i * 2048 + h * 128 + lane] = o0;
        imv[(size_t)i * 2048 + h * 128 + lane + 64] = o1;
    }
}

extern "C" void kernel_launch(void* const* d_in, const int* in_sizes, int n_in,
                              void* d_out, int out_size, void* d_ws, size_t ws_size,
                              hipStream_t stream) {
    const float* x      = (const float*)d_in[0];
    const float* weight = (const float*)d_in[1];
    const float* bias   = (const float*)d_in[2];
    const float* cls    = (const float*)d_in[3];
    const float* Wqkv   = (const float*)d_in[4];
    const float* Wo     = (const float*)d_in[5];
    const float* ln1_g  = (const float*)d_in[6];
    const float* ln1_b  = (const float*)d_in[7];
    const float* ln2_g  = (const float*)d_in[8];
    const float* ln2_b  = (const float*)d_in[9];
    const float* ln3_g  = (const float*)d_in[10];
    const float* ln3_b  = (const float*)d_in[11];
    const float* fc1_w  = (const float*)d_in[12];
    const float* fc1_b  = (const float*)d_in[13];
    const float* fc2_w  = (const float*)d_in[14];
    const float* fc2_b  = (const float*)d_in[15];
    float* out = (float*)d_out;

    float* ws     = (float*)d_ws;
    float* ss     = ws;                  // 34816
    float* altx   = ws + 34816;          // 32768
    float* imv    = ws + 67584;          // 34816
    float* qkv    = ws + 102400;         // 104448
    float* Pf     = ws + 206848;         // 139264 (fc1 raw)
    float* tbuf   = ws + 346112;         // 139264 (gelu out)
    float* ln1buf = ws + 485376;         // 34816
    float* ln2buf = ws + 520192;         // 34816
    float* Pg     = ws + 555008;         // 139264 (k-split planes)

    k0_init<<<136, 256, 0, stream>>>(x, bias, cls, ss, altx);
    // ss[1:17] += altx @ weight.T  (2 planes [16][2048], CH=4)
    gemvP<16, 4><<<dim3(512, 2), 256, 0, stream>>>(weight, altx, Pg, 2048, 2048);
    redln<<<17, 256, 0, stream>>>(Pg, 2, 1, 32768, nullptr, ss, ln1_g, ln1_b, ln1buf);

    for (int k = 0; k < 4; ++k) {
        // qkv = Wqkv[k] @ ln1buf  (direct, L=6144, CH=8)
        gemvP<17, 8><<<dim3(1536, 1), 256, 0, stream>>>(
            Wqkv + (size_t)k * 12582912, ln1buf, qkv, 6144, 2048);
        attn_kernel<<<16, 64, 0, stream>>>(qkv, imv);
        // Pg = imv @ Wo[k].T  (2 planes [17][2048], CH=4)
        gemvP<17, 4><<<dim3(512, 2), 256, 0, stream>>>(
            Wo + (size_t)k * 4194304, imv, Pg, 2048, 2048);
        redln<<<17, 256, 0, stream>>>(Pg, 2, 0, 34816, nullptr, ss, ln2_g, ln2_b, ln2buf);
        // Pf = fc1_w @ ln2buf  (direct raw, L=8192, CH=8)
        gemvP<17, 8><<<dim3(2048, 1), 256, 0, stream>>>(fc1_w, ln2buf, Pf, 8192, 2048);
        red_gelu<<<544, 256, 0, stream>>>(Pf, fc1_b, tbuf);
        // Pg = fc2_w @ tbuf  (4 planes [17][2048], K=8192, CH=8)
        gemvP<17, 8><<<dim3(512, 4), 256, 0, stream>>>(fc2_w, tbuf, Pg, 2048, 8192);
        if (k < 3)
            redln<<<17, 256, 0, stream>>>(Pg, 4, 0, 34816, fc2_b, ss, ln1_g, ln1_b, ln1buf);
        else
            redln<<<17, 256, 0, stream>>>(Pg, 4, 0, 34816, fc2_b, ss, ln3_g, ln3_b, out);
    }
}